// Round 18
// baseline (91.537 us; speedup 1.0000x reference)
//
#include <hip/hip_runtime.h>
#include <hip/hip_bf16.h>

#define NN 8192
#define TT 1024
#define WW 64
#define HH 256
#define DTF (1.0f/24.0f)

typedef __attribute__((ext_vector_type(8))) short short8_t;   // 8 bf16 (4 VGPR)
typedef __attribute__((ext_vector_type(4))) short short4_t;   // 4 bf16 (2 VGPR)
typedef __attribute__((ext_vector_type(4))) float f32x4_t;

__device__ __forceinline__ float sigmoidf_(float v) { return 1.0f / (1.0f + __expf(-v)); }

__device__ __forceinline__ short f2bf(float f) {
    __hip_bfloat16 h = __float2bfloat16(f);
    short s; __builtin_memcpy(&s, &h, sizeof(short));
    return s;
}

// LDS element-index swizzle (8-short granule, keeps b128 aligned)
__device__ __forceinline__ int swz(int e) { return e ^ (((e >> 6) & 3) << 3); }

// nontemporal helpers (cache-policy only; bitwise-identical data)
__device__ __forceinline__ f32x4_t ntload4(const float* p) {
    return __builtin_nontemporal_load((const f32x4_t*)p);
}
__device__ __forceinline__ void ntstore4(float* p, f32x4_t v) {
    __builtin_nontemporal_store(v, (f32x4_t*)p);
}

// ---------------- w2 -> bf16 B-frag-ordered table (one-time) ----------------
__global__ __launch_bounds__(256) void w2bf_kernel(
    const float* __restrict__ w2, short* __restrict__ w2f)
{
    const int gid  = blockIdx.x * 256 + threadIdx.x;   // 0..8191
    const int ks   = gid >> 10;
    const int rest = gid & 1023;
    const int nt   = rest >> 6;
    const int lane = rest & 63;
    const int lg = lane >> 4, lc = lane & 15;
    short8_t v;
#pragma unroll
    for (int j = 0; j < 8; ++j)
        v[j] = f2bf(w2[(ks * 32 + 8 * lg + j) * HH + nt * 16 + lc]);
    *(short8_t*)&w2f[(size_t)gid * 8] = v;
}

// ---------------- MLP (MFMA layer-2) -> (k,xw) -> IRF + conv frag table ----------------
__global__ __launch_bounds__(256) void mlp_mfma(
    const float* __restrict__ phys,
    const float* __restrict__ w1, const float* __restrict__ b1,
    const short* __restrict__ w2f, const float* __restrict__ b2,
    const float* __restrict__ w3, const float* __restrict__ b3,
    float* __restrict__ irf, short* __restrict__ irfB)
{
    const int t    = threadIdx.x;
    const int wv   = t >> 6;
    const int lane = t & 63;
    const int lc = lane & 15, lg = lane >> 4;
    const int n0 = blockIdx.x * 16;

    __shared__ float s_phys[16 * 3];
    __shared__ __align__(16) short s_h1b[16 * 256];   // 8KB, swizzled bf16
    __shared__ float s_red[4][16][2];
    __shared__ float s_kxw[16][2];
    __shared__ __align__(16) float s_irf[16 * 64];    // 4KB

    if (t < 48) s_phys[t] = phys[n0 * 3 + t];
    __syncthreads();

    // layer 1
    {
        const int m  = t >> 4;
        const int i0 = (t & 15) * 16;
        const float p0 = s_phys[m*3+0], p1 = s_phys[m*3+1], p2 = s_phys[m*3+2];
        float h[16];
#pragma unroll
        for (int u = 0; u < 4; ++u) {
            const float4 a0 = *(const float4*)&w1[0*HH + i0 + 4*u];
            const float4 a1 = *(const float4*)&w1[1*HH + i0 + 4*u];
            const float4 a2 = *(const float4*)&w1[2*HH + i0 + 4*u];
            const float4 bb = *(const float4*)&b1[i0 + 4*u];
            h[4*u+0] = fmaxf(p0*a0.x + p1*a1.x + p2*a2.x + bb.x, 0.f);
            h[4*u+1] = fmaxf(p0*a0.y + p1*a1.y + p2*a2.y + bb.y, 0.f);
            h[4*u+2] = fmaxf(p0*a0.z + p1*a1.z + p2*a2.z + bb.z, 0.f);
            h[4*u+3] = fmaxf(p0*a0.w + p1*a1.w + p2*a2.w + bb.w, 0.f);
        }
#pragma unroll
        for (int u = 0; u < 2; ++u) {
            short8_t s;
#pragma unroll
            for (int j = 0; j < 8; ++j) s[j] = f2bf(h[8*u + j]);
            *(short8_t*)&s_h1b[m * 256 + ((i0 + 8*u) ^ ((m & 7) << 3))] = s;
        }
    }
    __syncthreads();

    // layer 2
    f32x4_t acc[4];
#pragma unroll
    for (int u = 0; u < 4; ++u) acc[u] = f32x4_t{0.f, 0.f, 0.f, 0.f};
    short8_t af[8];
#pragma unroll
    for (int ks = 0; ks < 8; ++ks)
        af[ks] = *(const short8_t*)&s_h1b[lc * 256 + ((ks*32 + 8*lg) ^ ((lc & 7) << 3))];
#pragma unroll
    for (int u = 0; u < 4; ++u) {
        const int nt = 4 * wv + u;
#pragma unroll
        for (int ks = 0; ks < 8; ++ks) {
            const short8_t bfr = *(const short8_t*)&w2f[(size_t)((ks*16 + nt)*64 + lane) * 8];
            acc[u] = __builtin_amdgcn_mfma_f32_16x16x32_bf16(af[ks], bfr, acc[u], 0, 0, 0);
        }
    }

    // layer 3
    float p3[4][2];
#pragma unroll
    for (int q = 0; q < 4; ++q) { p3[q][0] = 0.f; p3[q][1] = 0.f; }
#pragma unroll
    for (int u = 0; u < 4; ++u) {
        const int j = (4*wv + u) * 16 + lc;
        const float b2v = b2[j];
        const float w30 = w3[j*2+0], w31 = w3[j*2+1];
#pragma unroll
        for (int q = 0; q < 4; ++q) {
            const float h2 = fmaxf(acc[u][q] + b2v, 0.f);
            p3[q][0] += h2 * w30; p3[q][1] += h2 * w31;
        }
    }
#pragma unroll
    for (int off = 8; off >= 1; off >>= 1)
#pragma unroll
        for (int q = 0; q < 4; ++q) {
            p3[q][0] += __shfl_xor(p3[q][0], off);
            p3[q][1] += __shfl_xor(p3[q][1], off);
        }
    if (lc == 0)
#pragma unroll
        for (int q = 0; q < 4; ++q) {
            s_red[wv][4*lg + q][0] = p3[q][0];
            s_red[wv][4*lg + q][1] = p3[q][1];
        }
    __syncthreads();

    if (t < 32) {
        const int m = t >> 1, d = t & 1;
        const float raw = s_red[0][m][d] + s_red[1][m][d] + s_red[2][m][d] + s_red[3][m][d] + b3[d];
        s_kxw[m][d] = (d == 0) ? sigmoidf_(raw) * 0.25f + 0.005f
                               : sigmoidf_(raw - 3.f) * 1.2f;
    }
    __syncthreads();

    // IRF
    {
        const int nd = t >> 4, l = t & 15;
        const float k = s_kxw[nd][0], xw = s_kxw[nd][1];
        const float delay = k * xw;
        const float tau   = fmaxf(k * (1.f - xw), 0.5f * DTF);
        float hv[4]; float s = 0.f;
#pragma unroll
        for (int u = 0; u < 4; ++u) {
            const float tf = (l + 16*u) * DTF;
            hv[u] = (tf >= delay) ? __expf(-(tf - delay) / tau) / tau : 0.f;
            s += hv[u];
        }
#pragma unroll
        for (int off = 8; off >= 1; off >>= 1) s += __shfl_xor(s, off);
        const float inv = 1.f / (s + 1e-8f);
        float* drow = irf + (size_t)(n0 + nd) * WW;
#pragma unroll
        for (int u = 0; u < 4; ++u) {
            const float v = hv[u] * inv;
            drow[l + 16*u]        = v;
            s_irf[nd*64 + l + 16*u] = v;
        }
    }
    __syncthreads();

    // conv frag table: irfB[n][p][L][j] = rfz[(L&15) - 8*(L>>4) - j + 16 + 32p]
    {
        const int nd = t >> 4, lb = t & 15;
        const float* sr = &s_irf[nd * 64];
        short* dst = irfB + (size_t)(n0 + nd) * 1536;
#pragma unroll
        for (int li = 0; li < 4; ++li) {
            const int L = 4*lb + li;
            const int Llc = L & 15, Llg = L >> 4;
#pragma unroll
            for (int p = 0; p < 3; ++p) {
                short8_t v;
#pragma unroll
                for (int j = 0; j < 8; ++j) {
                    const int idx = Llc - 8*Llg - j + 16 + 32*p;
                    v[j] = f2bf((idx >= 0 && idx < 64) ? sr[idx & 63] : 0.f);
                }
                *(short8_t*)&dst[(size_t)(p*64 + L) * 8] = v;
            }
        }
    }
}

// ================= MFMA conv machinery (transposed product D') =================
#define LROW 1152   // 80-elem zero prologue + 1024 row, shorts, swizzled

__device__ __forceinline__ void zero_prologue(short* sab, int tid) {
    if (tid < 10) {
        short8_t z = {0,0,0,0,0,0,0,0};
        *(short8_t*)&sab[swz(8 * tid)] = z;
    }
}

// round-15 staging: lane reads 16 consecutive floats (4x f4, 64B lane stride);
// all fetched lines are fully consumed across the 4 unrolled loads.
__device__ __forceinline__ void load16_nt(const float* __restrict__ src, int tid, float (&a)[16]) {
#pragma unroll
    for (int u = 0; u < 4; ++u) {
        const f32x4_t v = ntload4(&src[16 * tid + 4 * u]);
        a[4*u+0] = v[0]; a[4*u+1] = v[1]; a[4*u+2] = v[2]; a[4*u+3] = v[3];
    }
}

__device__ __forceinline__ void stage16(short* sab, const float (&a)[16], int tid) {
#pragma unroll
    for (int u = 0; u < 2; ++u) {
        short8_t s;
#pragma unroll
        for (int j = 0; j < 8; ++j) s[j] = f2bf(a[8*u + j]);
        *(short8_t*)&sab[swz(80 + 16 * tid + 8 * u)] = s;
    }
}

__device__ __forceinline__ void load_bfrags(const short* __restrict__ irfB, int n,
                                            int tid, short8_t (&bf)[3]) {
#pragma unroll
    for (int p = 0; p < 3; ++p)
        bf[p] = *(const short8_t*)&irfB[(size_t)n * 1536 + (size_t)(p*64 + tid) * 8];
}

// 12 MFMAs; EB = 80 + 16*(lane&15) + 8*(lane>>4); irf=A', data=B' (D' transposed product)
__device__ __forceinline__ void conv_mfma3(const short* sab, const short8_t (&bf)[3],
                                           int EB, f32x4_t (&acc)[4]) {
#pragma unroll
    for (int S = 0; S < 4; ++S) {
#pragma unroll
        for (int p = 0; p < 3; ++p) {
            const short8_t af = *(const short8_t*)&sab[swz(EB + 256 * S - 16 * (2 * p + 1))];
            acc[S] = __builtin_amdgcn_mfma_f32_16x16x32_bf16(bf[p], af, acc[S], 0, 0, 0);
        }
    }
}

// ---------------- fat pass (round-15 structure + nontemporal hints) ----------------
// r < 1366:            L6-int n=1365+(r>>1), children 5461..8191 (2047's 4th OOB)
// 1366 <= r < 3072:    L5-fused n=512+((r-1366)>>1), children 2049..5460 (leaves)
// r >= 3072 (2 tasks): leaf n=2048
// NT policy: x reads = streamed once -> nt loads; child out rows = never re-read
// by any kernel -> nt stores. Own-row stores (read by mid/tail3) stay cached.
__global__ __launch_bounds__(256) void route_lf6p(
    const float* __restrict__ x, const short* __restrict__ irfB,
    float* __restrict__ out)
{
    const int wid = threadIdx.x >> 6;
    const int tid = threadIdx.x & 63;
    const int r   = blockIdx.x * 4 + wid;
    if (r >= 3074) return;

    const int lc = tid & 15, lg = tid >> 4;
    const int EB = 80 + 16 * lc + 8 * lg;
    const int DP = 16 * lc + 4 * lg;

    __shared__ __align__(16) short s_a[4][LROW];
    short* sab = s_a[wid];
    zero_prologue(sab, tid);

    float a16[16];
    short8_t bf[3];

    if (r < 3072) {
        const bool isl6 = (r < 1366);
        const int idx = isl6 ? r : (r - 1366);
        const int b = idx & 1;
        const int n = __builtin_amdgcn_readfirstlane((isl6 ? 1365 : 512) + (idx >> 1));
        const size_t rowb = ((size_t)b * NN + n) * TT;
        const int c0 = 4 * n + 1;

        f32x4_t accD[4];
#pragma unroll
        for (int S = 0; S < 4; ++S)
            accD[S] = ntload4(&x[rowb + 256 * S + DP]);

#pragma unroll 1
        for (int e = 0; e < 4; ++e) {
            const int c = c0 + e;
            if (c < NN) {            // only node 2047's 4th child (8192) is OOB
                const size_t crow = ((size_t)b * NN + c) * TT;
                load16_nt(x + crow, tid, a16);
                stage16(sab, a16, tid);
                load_bfrags(irfB, c, tid, bf);
                f32x4_t accT[4];
#pragma unroll
                for (int S = 0; S < 4; ++S) accT[S] = f32x4_t{0.f, 0.f, 0.f, 0.f};
                conv_mfma3(sab, bf, EB, accT);
#pragma unroll
                for (int S = 0; S < 4; ++S) {
                    ntstore4(&out[crow + 256 * S + DP], accT[S]);
                    accD[S] += accT[S];
                }
            }
        }

#pragma unroll
        for (int S = 0; S < 4; ++S) {
            short4_t s4;
#pragma unroll
            for (int q = 0; q < 4; ++q) s4[q] = f2bf(accD[S][q]);
            *(short4_t*)&sab[swz(80 + 256 * S + DP)] = s4;
        }

        load_bfrags(irfB, n, tid, bf);
        f32x4_t accF[4];
#pragma unroll
        for (int S = 0; S < 4; ++S) accF[S] = f32x4_t{0.f, 0.f, 0.f, 0.f};
        conv_mfma3(sab, bf, EB, accF);
#pragma unroll
        for (int S = 0; S < 4; ++S)
            *(f32x4_t*)&out[rowb + 256 * S + DP] = accF[S];
    } else {
        const int b = r - 3072;
        const int n = 2048;
        const size_t rowb = ((size_t)b * NN + n) * TT;

        load16_nt(x + rowb, tid, a16);
        stage16(sab, a16, tid);
        load_bfrags(irfB, n, tid, bf);
        f32x4_t accF[4];
#pragma unroll
        for (int S = 0; S < 4; ++S) accF[S] = f32x4_t{0.f, 0.f, 0.f, 0.f};
        conv_mfma3(sab, bf, EB, accF);
#pragma unroll
        for (int S = 0; S < 4; ++S)
            *(f32x4_t*)&out[rowb + 256 * S + DP] = accF[S];
    }
}

// ---------------- mid-small: L5 nodes 341..511, children (1365..2047) from out ----------------
__global__ __launch_bounds__(256) void route_mid_mfma(
    const float* __restrict__ x, const short* __restrict__ irfB,
    float* __restrict__ out, int base, int n_tasks)
{
    const int wid = threadIdx.x >> 6;
    const int tid = threadIdx.x & 63;
    const int r   = blockIdx.x * 4 + wid;
    if (r >= n_tasks) return;

    const int lc = tid & 15, lg = tid >> 4;
    const int EB = 80 + 16 * lc + 8 * lg;
    const int DP = 16 * lc + 4 * lg;

    __shared__ __align__(16) short s_a[4][LROW];
    short* sab = s_a[wid];
    zero_prologue(sab, tid);

    const int b = r & 1;
    const int n = __builtin_amdgcn_readfirstlane(base + (r >> 1));
    const size_t rowb = ((size_t)b * NN + n) * TT;
    const int c0 = 4 * n + 1;

    float a16[16];
#pragma unroll
    for (int u = 0; u < 4; ++u) {
        float4 v = *(const float4*)&x[rowb + 16 * tid + 4 * u];
#pragma unroll
        for (int e = 0; e < 4; ++e) {
            const float4 w = *(const float4*)&out[((size_t)b * NN + c0 + e) * TT + 16 * tid + 4 * u];
            v.x += w.x; v.y += w.y; v.z += w.z; v.w += w.w;
        }
        a16[4*u+0] = v.x; a16[4*u+1] = v.y; a16[4*u+2] = v.z; a16[4*u+3] = v.w;
    }
    stage16(sab, a16, tid);

    short8_t bf[3];
    load_bfrags(irfB, n, tid, bf);
    f32x4_t accF[4];
#pragma unroll
    for (int S = 0; S < 4; ++S) accF[S] = f32x4_t{0.f, 0.f, 0.f, 0.f};
    conv_mfma3(sab, bf, EB, accF);
#pragma unroll
    for (int S = 0; S < 4; ++S)
        *(f32x4_t*)&out[rowb + 256 * S + DP] = accF[S];
}

// ---------------- tail3 (L4+L3+L2), MFMA conv ----------------
__global__ __launch_bounds__(256) void route_tail3_mfma(
    const float* __restrict__ x, const short* __restrict__ irfB,
    float* __restrict__ out)
{
    const int wid = threadIdx.x >> 6;
    const int tid = threadIdx.x & 63;
    const int b   = blockIdx.x & 1;
    const int p   = 5 + (int)(blockIdx.x >> 1);

    const int lc = tid & 15, lg = tid >> 4;
    const int EB = 80 + 16 * lc + 8 * lg;
    const int DP = 16 * lc + 4 * lg;

    __shared__ __align__(16) short s_a[4][LROW];   // 9 KB
    __shared__ __align__(16) float s_ch[4][TT];    // 16 KB
    short* sab = s_a[wid];
    zero_prologue(sab, tid);

    const int cw = 4 * p + 1 + wid;                // L3: 21..84
    const size_t crow = ((size_t)b * NN + cw) * TT;

    float a16[16];
    short8_t bf[3];

    f32x4_t accCW[4];
#pragma unroll
    for (int S = 0; S < 4; ++S)
        accCW[S] = *(const f32x4_t*)&x[crow + 256 * S + DP];

#pragma unroll 1
    for (int k = 0; k < 4; ++k) {
        const int g = 4 * cw + 1 + k;
        const size_t grow = ((size_t)b * NN + g) * TT;
#pragma unroll
        for (int u = 0; u < 4; ++u) {
            float4 v = *(const float4*)&x[grow + 16 * tid + 4 * u];
#pragma unroll
            for (int e = 0; e < 4; ++e) {
                const float4 w = *(const float4*)&out[((size_t)b * NN + (4 * g + 1 + e)) * TT + 16 * tid + 4 * u];
                v.x += w.x; v.y += w.y; v.z += w.z; v.w += w.w;
            }
            a16[4*u+0] = v.x; a16[4*u+1] = v.y; a16[4*u+2] = v.z; a16[4*u+3] = v.w;
        }
        stage16(sab, a16, tid);
        load_bfrags(irfB, g, tid, bf);
        f32x4_t accT[4];
#pragma unroll
        for (int S = 0; S < 4; ++S) accT[S] = f32x4_t{0.f, 0.f, 0.f, 0.f};
        conv_mfma3(sab, bf, EB, accT);
#pragma unroll
        for (int S = 0; S < 4; ++S) {
            *(f32x4_t*)&out[grow + 256 * S + DP] = accT[S];
            accCW[S] += accT[S];
        }
    }

#pragma unroll
    for (int S = 0; S < 4; ++S) {
        short4_t s4;
#pragma unroll
        for (int q = 0; q < 4; ++q) s4[q] = f2bf(accCW[S][q]);
        *(short4_t*)&sab[swz(80 + 256 * S + DP)] = s4;
    }
    load_bfrags(irfB, cw, tid, bf);
    f32x4_t accB[4];
#pragma unroll
    for (int S = 0; S < 4; ++S) accB[S] = f32x4_t{0.f, 0.f, 0.f, 0.f};
    conv_mfma3(sab, bf, EB, accB);
#pragma unroll
    for (int S = 0; S < 4; ++S) {
        *(f32x4_t*)&out[crow + 256 * S + DP] = accB[S];
        *(f32x4_t*)&s_ch[wid][256 * S + DP]  = accB[S];
    }

    __syncthreads();

    if (wid == 0) {
        const size_t prow = ((size_t)b * NN + p) * TT;
#pragma unroll
        for (int u = 0; u < 4; ++u) {
            float4 v = *(const float4*)&x[prow + 16 * tid + 4 * u];
#pragma unroll
            for (int w2 = 0; w2 < 4; ++w2) {
                const float4 cc = *(const float4*)&s_ch[w2][16 * tid + 4 * u];
                v.x += cc.x; v.y += cc.y; v.z += cc.z; v.w += cc.w;
            }
            a16[4*u+0] = v.x; a16[4*u+1] = v.y; a16[4*u+2] = v.z; a16[4*u+3] = v.w;
        }
        stage16(sab, a16, tid);
        load_bfrags(irfB, p, tid, bf);
        f32x4_t accF[4];
#pragma unroll
        for (int S = 0; S < 4; ++S) accF[S] = f32x4_t{0.f, 0.f, 0.f, 0.f};
        conv_mfma3(sab, bf, EB, accF);
#pragma unroll
        for (int S = 0; S < 4; ++S)
            *(f32x4_t*)&out[prow + 256 * S + DP] = accF[S];
    }
}

// ================= scalar fp32 tail2 (L1 + root; large magnitudes) =================
__device__ __forceinline__ void load_rf(const float* __restrict__ irf, int n, float (&rf)[WW]) {
    const float* irp = irf + (size_t)n * WW;
#pragma unroll
    for (int i = 0; i < WW / 4; ++i) {
        const float4 f = *(const float4*)&irp[4 * i];
        rf[4*i+0] = f.x; rf[4*i+1] = f.y; rf[4*i+2] = f.z; rf[4*i+3] = f.w;
    }
}

__device__ __forceinline__ void wave_conv16(const float (&a)[16], const float (&rf)[WW],
                                            float (&y)[16], int tid)
{
#pragma unroll
    for (int j = 0; j < 16; ++j) y[j] = 0.0f;
#pragma unroll
    for (int m = 0; m < 16; ++m)
#pragma unroll
        for (int j = m; j < 16; ++j)
            y[j] += rf[j - m] * a[m];
#pragma unroll
    for (int d = 1; d <= 4; ++d) {
        float h[16];
#pragma unroll
        for (int m = 0; m < 16; ++m) {
            const float ha = __shfl(a[m], tid - d);
            h[m] = (tid >= d) ? ha : 0.0f;
        }
        if (d < 4) {
#pragma unroll
            for (int m = 0; m < 16; ++m)
#pragma unroll
                for (int j = 0; j < 16; ++j)
                    y[j] += rf[j + 16 * d - m] * h[m];
        } else {
#pragma unroll
            for (int m = 1; m < 16; ++m)
#pragma unroll
                for (int j = 0; j < m; ++j)
                    y[j] += rf[j + WW - m] * h[m];
        }
    }
}

__global__ __launch_bounds__(256) void route_tail2(
    const float* __restrict__ x, const float* __restrict__ irf,
    float* __restrict__ out)
{
    const int wid = threadIdx.x >> 6;
    const int tid = threadIdx.x & 63;
    const int b   = blockIdx.x;

    __shared__ __align__(16) float s_ch[4][TT];

    const int cw = 1 + wid;
    const size_t crow = ((size_t)b * NN + cw) * TT;
    const int loc = tid * 16;

    float rf[WW], a[16], y[16];

#pragma unroll
    for (int u = 0; u < 4; ++u) {
        float4 v = *(const float4*)&x[crow + loc + 4 * u];
#pragma unroll
        for (int e = 0; e < 4; ++e) {
            const float4 w = *(const float4*)&out[((size_t)b * NN + (4 * cw + 1 + e)) * TT + loc + 4 * u];
            v.x += w.x; v.y += w.y; v.z += w.z; v.w += w.w;
        }
        a[4*u+0] = v.x; a[4*u+1] = v.y; a[4*u+2] = v.z; a[4*u+3] = v.w;
    }
    load_rf(irf, cw, rf);
    wave_conv16(a, rf, y, tid);
#pragma unroll
    for (int u = 0; u < 4; ++u) {
        const float4 f = make_float4(y[4*u+0], y[4*u+1], y[4*u+2], y[4*u+3]);
        *(float4*)&out[crow + loc + 4 * u] = f;
        *(float4*)&s_ch[wid][loc + 4 * u]  = f;
    }

    __syncthreads();

    if (wid == 0) {
        const size_t prow = (size_t)b * NN * TT;
#pragma unroll
        for (int u = 0; u < 4; ++u) {
            float4 v = *(const float4*)&x[prow + loc + 4 * u];
#pragma unroll
            for (int w2 = 0; w2 < 4; ++w2) {
                const float4 cc = *(const float4*)&s_ch[w2][loc + 4 * u];
                v.x += cc.x; v.y += cc.y; v.z += cc.z; v.w += cc.w;
            }
            a[4*u+0] = v.x; a[4*u+1] = v.y; a[4*u+2] = v.z; a[4*u+3] = v.w;
        }
        load_rf(irf, 0, rf);
        wave_conv16(a, rf, y, tid);
#pragma unroll
        for (int u = 0; u < 4; ++u)
            *(float4*)&out[prow + loc + 4 * u] = make_float4(y[4*u+0], y[4*u+1], y[4*u+2], y[4*u+3]);
    }
}

extern "C" void kernel_launch(void* const* d_in, const int* in_sizes, int n_in,
                              void* d_out, int out_size, void* d_ws, size_t ws_size,
                              hipStream_t stream) {
    const float* x    = (const float*)d_in[0];
    const float* phys = (const float*)d_in[1];
    const float* w1   = (const float*)d_in[2];
    const float* b1   = (const float*)d_in[3];
    const float* w2   = (const float*)d_in[4];
    const float* b2   = (const float*)d_in[5];
    const float* w3   = (const float*)d_in[6];
    const float* b3   = (const float*)d_in[7];
    // d_in[8] = parent, d_in[9] = depth: fixed 4-ary heap tree (children 4n+1..4n+4)
    // levels: L0:0 L1:1-4 L2:5-20 L3:21-84 L4:85-340 L5:341-1364
    //         d6:1365-5460 (internal 1365-2047, leaves 2048-5460) d7:5461-8191 (leaves)

    float* out = (float*)d_out;
    // ws layout: irf fp32 [0,2MB) | w2f bf16 [2MB,+128KB) | irfB [4MB,+24MB)
    float* irf  = (float*)d_ws;
    short* w2f  = (short*)((char*)d_ws + (2u << 20));
    short* irfB = (short*)((char*)d_ws + (4u << 20));

    w2bf_kernel<<<32, 256, 0, stream>>>(w2, w2f);
    mlp_mfma<<<512, 256, 0, stream>>>(phys, w1, b1, w2f, b2, w3, b3, irf, irfB);

    // 1) fat pass: L6-int (1366) + L5-fused n=512..1364 (1706) + leaf 2048 (2) = 3074 tasks
    route_lf6p<<<(3074 + 3) / 4, 256, 0, stream>>>(x, irfB, out);
    // 2) mid-small: L5 nodes 341..511 (342 tasks), children from out
    route_mid_mfma<<<(342 + 3) / 4, 256, 0, stream>>>(x, irfB, out, 341, 342);
    // 3) L4+L3+L2 fused per L2 node (MFMA)
    route_tail3_mfma<<<32, 256, 0, stream>>>(x, irfB, out);
    // 4) L1+L0 (fp32 scalar, root precision)
    route_tail2<<<2, 256, 0, stream>>>(x, irf, out);
}

// Round 19
// 77.941 us; speedup vs baseline: 1.1744x; 1.1744x over previous
//
#include <hip/hip_runtime.h>
#include <hip/hip_bf16.h>

#define NN 8192
#define TT 1024
#define WW 64
#define HH 256
#define DTF (1.0f/24.0f)

typedef __attribute__((ext_vector_type(8))) short short8_t;   // 8 bf16 (4 VGPR)
typedef __attribute__((ext_vector_type(4))) short short4_t;   // 4 bf16 (2 VGPR)
typedef __attribute__((ext_vector_type(4))) float f32x4_t;

__device__ __forceinline__ float sigmoidf_(float v) { return 1.0f / (1.0f + __expf(-v)); }

__device__ __forceinline__ short f2bf(float f) {
    __hip_bfloat16 h = __float2bfloat16(f);
    short s; __builtin_memcpy(&s, &h, sizeof(short));
    return s;
}

// LDS element-index swizzle (8-short granule, keeps b128 aligned)
__device__ __forceinline__ int swz(int e) { return e ^ (((e >> 6) & 3) << 3); }

// ---------------- MLP (MFMA layer-2) -> (k,xw) -> IRF + conv frag table ----------------
// w2 gathered directly in frag order (L2-resident 256KB) — no separate w2bf pass.
__global__ __launch_bounds__(256) void mlp_mfma(
    const float* __restrict__ phys,
    const float* __restrict__ w1, const float* __restrict__ b1,
    const float* __restrict__ w2, const float* __restrict__ b2,
    const float* __restrict__ w3, const float* __restrict__ b3,
    float* __restrict__ irf, short* __restrict__ irfB)
{
    const int t    = threadIdx.x;
    const int wv   = t >> 6;
    const int lane = t & 63;
    const int lc = lane & 15, lg = lane >> 4;
    const int n0 = blockIdx.x * 16;

    __shared__ float s_phys[16 * 3];
    __shared__ __align__(16) short s_h1b[16 * 256];   // 8KB, swizzled bf16
    __shared__ float s_red[4][16][2];
    __shared__ float s_kxw[16][2];
    __shared__ __align__(16) float s_irf[16 * 64];    // 4KB

    if (t < 48) s_phys[t] = phys[n0 * 3 + t];
    __syncthreads();

    // layer 1
    {
        const int m  = t >> 4;
        const int i0 = (t & 15) * 16;
        const float p0 = s_phys[m*3+0], p1 = s_phys[m*3+1], p2 = s_phys[m*3+2];
        float h[16];
#pragma unroll
        for (int u = 0; u < 4; ++u) {
            const float4 a0 = *(const float4*)&w1[0*HH + i0 + 4*u];
            const float4 a1 = *(const float4*)&w1[1*HH + i0 + 4*u];
            const float4 a2 = *(const float4*)&w1[2*HH + i0 + 4*u];
            const float4 bb = *(const float4*)&b1[i0 + 4*u];
            h[4*u+0] = fmaxf(p0*a0.x + p1*a1.x + p2*a2.x + bb.x, 0.f);
            h[4*u+1] = fmaxf(p0*a0.y + p1*a1.y + p2*a2.y + bb.y, 0.f);
            h[4*u+2] = fmaxf(p0*a0.z + p1*a1.z + p2*a2.z + bb.z, 0.f);
            h[4*u+3] = fmaxf(p0*a0.w + p1*a1.w + p2*a2.w + bb.w, 0.f);
        }
#pragma unroll
        for (int u = 0; u < 2; ++u) {
            short8_t s;
#pragma unroll
            for (int j = 0; j < 8; ++j) s[j] = f2bf(h[8*u + j]);
            *(short8_t*)&s_h1b[m * 256 + ((i0 + 8*u) ^ ((m & 7) << 3))] = s;
        }
    }
    __syncthreads();

    // layer 2: wave wv owns nt = 4wv..4wv+3; w2 gathered in B-frag order
    f32x4_t acc[4];
#pragma unroll
    for (int u = 0; u < 4; ++u) acc[u] = f32x4_t{0.f, 0.f, 0.f, 0.f};
    short8_t af[8];
#pragma unroll
    for (int ks = 0; ks < 8; ++ks)
        af[ks] = *(const short8_t*)&s_h1b[lc * 256 + ((ks*32 + 8*lg) ^ ((lc & 7) << 3))];
#pragma unroll
    for (int u = 0; u < 4; ++u) {
        const int nt = 4 * wv + u;
#pragma unroll
        for (int ks = 0; ks < 8; ++ks) {
            short8_t bfr;
#pragma unroll
            for (int j = 0; j < 8; ++j)
                bfr[j] = f2bf(w2[(ks*32 + 8*lg + j) * HH + nt*16 + lc]);
            acc[u] = __builtin_amdgcn_mfma_f32_16x16x32_bf16(af[ks], bfr, acc[u], 0, 0, 0);
        }
    }

    // layer 3
    float p3[4][2];
#pragma unroll
    for (int q = 0; q < 4; ++q) { p3[q][0] = 0.f; p3[q][1] = 0.f; }
#pragma unroll
    for (int u = 0; u < 4; ++u) {
        const int j = (4*wv + u) * 16 + lc;
        const float b2v = b2[j];
        const float w30 = w3[j*2+0], w31 = w3[j*2+1];
#pragma unroll
        for (int q = 0; q < 4; ++q) {
            const float h2 = fmaxf(acc[u][q] + b2v, 0.f);
            p3[q][0] += h2 * w30; p3[q][1] += h2 * w31;
        }
    }
#pragma unroll
    for (int off = 8; off >= 1; off >>= 1)
#pragma unroll
        for (int q = 0; q < 4; ++q) {
            p3[q][0] += __shfl_xor(p3[q][0], off);
            p3[q][1] += __shfl_xor(p3[q][1], off);
        }
    if (lc == 0)
#pragma unroll
        for (int q = 0; q < 4; ++q) {
            s_red[wv][4*lg + q][0] = p3[q][0];
            s_red[wv][4*lg + q][1] = p3[q][1];
        }
    __syncthreads();

    if (t < 32) {
        const int m = t >> 1, d = t & 1;
        const float raw = s_red[0][m][d] + s_red[1][m][d] + s_red[2][m][d] + s_red[3][m][d] + b3[d];
        s_kxw[m][d] = (d == 0) ? sigmoidf_(raw) * 0.25f + 0.005f
                               : sigmoidf_(raw - 3.f) * 1.2f;
    }
    __syncthreads();

    // IRF
    {
        const int nd = t >> 4, l = t & 15;
        const float k = s_kxw[nd][0], xw = s_kxw[nd][1];
        const float delay = k * xw;
        const float tau   = fmaxf(k * (1.f - xw), 0.5f * DTF);
        float hv[4]; float s = 0.f;
#pragma unroll
        for (int u = 0; u < 4; ++u) {
            const float tf = (l + 16*u) * DTF;
            hv[u] = (tf >= delay) ? __expf(-(tf - delay) / tau) / tau : 0.f;
            s += hv[u];
        }
#pragma unroll
        for (int off = 8; off >= 1; off >>= 1) s += __shfl_xor(s, off);
        const float inv = 1.f / (s + 1e-8f);
        float* drow = irf + (size_t)(n0 + nd) * WW;
#pragma unroll
        for (int u = 0; u < 4; ++u) {
            const float v = hv[u] * inv;
            drow[l + 16*u]        = v;
            s_irf[nd*64 + l + 16*u] = v;
        }
    }
    __syncthreads();

    // conv frag table: irfB[n][p][L][j] = rfz[(L&15) - 8*(L>>4) - j + 16 + 32p]
    {
        const int nd = t >> 4, lb = t & 15;
        const float* sr = &s_irf[nd * 64];
        short* dst = irfB + (size_t)(n0 + nd) * 1536;
#pragma unroll
        for (int li = 0; li < 4; ++li) {
            const int L = 4*lb + li;
            const int Llc = L & 15, Llg = L >> 4;
#pragma unroll
            for (int p = 0; p < 3; ++p) {
                short8_t v;
#pragma unroll
                for (int j = 0; j < 8; ++j) {
                    const int idx = Llc - 8*Llg - j + 16 + 32*p;
                    v[j] = f2bf((idx >= 0 && idx < 64) ? sr[idx & 63] : 0.f);
                }
                *(short8_t*)&dst[(size_t)(p*64 + L) * 8] = v;
            }
        }
    }
}

// ================= MFMA conv machinery (transposed product D') =================
#define LROW 1152   // 80-elem zero prologue + 1024 row, shorts, swizzled

__device__ __forceinline__ void zero_prologue(short* sab, int tid) {
    if (tid < 10) {
        short8_t z = {0,0,0,0,0,0,0,0};
        *(short8_t*)&sab[swz(8 * tid)] = z;
    }
}

__device__ __forceinline__ void load16(const float* __restrict__ src, int tid, float (&a)[16]) {
#pragma unroll
    for (int u = 0; u < 4; ++u) {
        const float4 v = *(const float4*)&src[16 * tid + 4 * u];
        a[4*u+0] = v.x; a[4*u+1] = v.y; a[4*u+2] = v.z; a[4*u+3] = v.w;
    }
}

__device__ __forceinline__ void stage16(short* sab, const float (&a)[16], int tid) {
#pragma unroll
    for (int u = 0; u < 2; ++u) {
        short8_t s;
#pragma unroll
        for (int j = 0; j < 8; ++j) s[j] = f2bf(a[8*u + j]);
        *(short8_t*)&sab[swz(80 + 16 * tid + 8 * u)] = s;
    }
}

__device__ __forceinline__ void load_bfrags(const short* __restrict__ irfB, int n,
                                            int tid, short8_t (&bf)[3]) {
#pragma unroll
    for (int p = 0; p < 3; ++p)
        bf[p] = *(const short8_t*)&irfB[(size_t)n * 1536 + (size_t)(p*64 + tid) * 8];
}

// 12 MFMAs; EB = 80 + 16*(lane&15) + 8*(lane>>4); irf=A', data=B' (D' transposed product)
__device__ __forceinline__ void conv_mfma3(const short* sab, const short8_t (&bf)[3],
                                           int EB, f32x4_t (&acc)[4]) {
#pragma unroll
    for (int S = 0; S < 4; ++S) {
#pragma unroll
        for (int p = 0; p < 3; ++p) {
            const short8_t af = *(const short8_t*)&sab[swz(EB + 256 * S - 16 * (2 * p + 1))];
            acc[S] = __builtin_amdgcn_mfma_f32_16x16x32_bf16(bf[p], af, acc[S], 0, 0, 0);
        }
    }
}

// ---------------- fat pass (round-15 structure, exact revert) ----------------
// r < 1366:            L6-int n=1365+(r>>1), children 5461..8191 (2047's 4th OOB)
// 1366 <= r < 3072:    L5-fused n=512+((r-1366)>>1), children 2049..5460 (leaves)
// r >= 3072 (2 tasks): leaf n=2048
__global__ __launch_bounds__(256) void route_lf6p(
    const float* __restrict__ x, const short* __restrict__ irfB,
    float* __restrict__ out)
{
    const int wid = threadIdx.x >> 6;
    const int tid = threadIdx.x & 63;
    const int r   = blockIdx.x * 4 + wid;
    if (r >= 3074) return;

    const int lc = tid & 15, lg = tid >> 4;
    const int EB = 80 + 16 * lc + 8 * lg;
    const int DP = 16 * lc + 4 * lg;

    __shared__ __align__(16) short s_a[4][LROW];
    short* sab = s_a[wid];
    zero_prologue(sab, tid);

    float a16[16];
    short8_t bf[3];

    if (r < 3072) {
        const bool isl6 = (r < 1366);
        const int idx = isl6 ? r : (r - 1366);
        const int b = idx & 1;
        const int n = __builtin_amdgcn_readfirstlane((isl6 ? 1365 : 512) + (idx >> 1));
        const size_t rowb = ((size_t)b * NN + n) * TT;
        const int c0 = 4 * n + 1;

        f32x4_t accD[4];
#pragma unroll
        for (int S = 0; S < 4; ++S)
            accD[S] = *(const f32x4_t*)&x[rowb + 256 * S + DP];

#pragma unroll 1
        for (int e = 0; e < 4; ++e) {
            const int c = c0 + e;
            if (c < NN) {            // only node 2047's 4th child (8192) is OOB
                const size_t crow = ((size_t)b * NN + c) * TT;
                load16(x + crow, tid, a16);
                stage16(sab, a16, tid);
                load_bfrags(irfB, c, tid, bf);
                f32x4_t accT[4];
#pragma unroll
                for (int S = 0; S < 4; ++S) accT[S] = f32x4_t{0.f, 0.f, 0.f, 0.f};
                conv_mfma3(sab, bf, EB, accT);
#pragma unroll
                for (int S = 0; S < 4; ++S) {
                    *(f32x4_t*)&out[crow + 256 * S + DP] = accT[S];
                    accD[S] += accT[S];
                }
            }
        }

#pragma unroll
        for (int S = 0; S < 4; ++S) {
            short4_t s4;
#pragma unroll
            for (int q = 0; q < 4; ++q) s4[q] = f2bf(accD[S][q]);
            *(short4_t*)&sab[swz(80 + 256 * S + DP)] = s4;
        }

        load_bfrags(irfB, n, tid, bf);
        f32x4_t accF[4];
#pragma unroll
        for (int S = 0; S < 4; ++S) accF[S] = f32x4_t{0.f, 0.f, 0.f, 0.f};
        conv_mfma3(sab, bf, EB, accF);
#pragma unroll
        for (int S = 0; S < 4; ++S)
            *(f32x4_t*)&out[rowb + 256 * S + DP] = accF[S];
    } else {
        const int b = r - 3072;
        const int n = 2048;
        const size_t rowb = ((size_t)b * NN + n) * TT;

        load16(x + rowb, tid, a16);
        stage16(sab, a16, tid);
        load_bfrags(irfB, n, tid, bf);
        f32x4_t accF[4];
#pragma unroll
        for (int S = 0; S < 4; ++S) accF[S] = f32x4_t{0.f, 0.f, 0.f, 0.f};
        conv_mfma3(sab, bf, EB, accF);
#pragma unroll
        for (int S = 0; S < 4; ++S)
            *(f32x4_t*)&out[rowb + 256 * S + DP] = accF[S];
    }
}

// ---------------- mid-small: L5 nodes 341..511, children (1365..2047) from out ----------------
__global__ __launch_bounds__(256) void route_mid_mfma(
    const float* __restrict__ x, const short* __restrict__ irfB,
    float* __restrict__ out, int base, int n_tasks)
{
    const int wid = threadIdx.x >> 6;
    const int tid = threadIdx.x & 63;
    const int r   = blockIdx.x * 4 + wid;
    if (r >= n_tasks) return;

    const int lc = tid & 15, lg = tid >> 4;
    const int EB = 80 + 16 * lc + 8 * lg;
    const int DP = 16 * lc + 4 * lg;

    __shared__ __align__(16) short s_a[4][LROW];
    short* sab = s_a[wid];
    zero_prologue(sab, tid);

    const int b = r & 1;
    const int n = __builtin_amdgcn_readfirstlane(base + (r >> 1));
    const size_t rowb = ((size_t)b * NN + n) * TT;
    const int c0 = 4 * n + 1;

    float a16[16];
#pragma unroll
    for (int u = 0; u < 4; ++u) {
        float4 v = *(const float4*)&x[rowb + 16 * tid + 4 * u];
#pragma unroll
        for (int e = 0; e < 4; ++e) {
            const float4 w = *(const float4*)&out[((size_t)b * NN + c0 + e) * TT + 16 * tid + 4 * u];
            v.x += w.x; v.y += w.y; v.z += w.z; v.w += w.w;
        }
        a16[4*u+0] = v.x; a16[4*u+1] = v.y; a16[4*u+2] = v.z; a16[4*u+3] = v.w;
    }
    stage16(sab, a16, tid);

    short8_t bf[3];
    load_bfrags(irfB, n, tid, bf);
    f32x4_t accF[4];
#pragma unroll
    for (int S = 0; S < 4; ++S) accF[S] = f32x4_t{0.f, 0.f, 0.f, 0.f};
    conv_mfma3(sab, bf, EB, accF);
#pragma unroll
    for (int S = 0; S < 4; ++S)
        *(f32x4_t*)&out[rowb + 256 * S + DP] = accF[S];
}

// ---------------- tail3 (L4+L3+L2), MFMA conv ----------------
__global__ __launch_bounds__(256) void route_tail3_mfma(
    const float* __restrict__ x, const short* __restrict__ irfB,
    float* __restrict__ out)
{
    const int wid = threadIdx.x >> 6;
    const int tid = threadIdx.x & 63;
    const int b   = blockIdx.x & 1;
    const int p   = 5 + (int)(blockIdx.x >> 1);

    const int lc = tid & 15, lg = tid >> 4;
    const int EB = 80 + 16 * lc + 8 * lg;
    const int DP = 16 * lc + 4 * lg;

    __shared__ __align__(16) short s_a[4][LROW];   // 9 KB
    __shared__ __align__(16) float s_ch[4][TT];    // 16 KB
    short* sab = s_a[wid];
    zero_prologue(sab, tid);

    const int cw = 4 * p + 1 + wid;                // L3: 21..84
    const size_t crow = ((size_t)b * NN + cw) * TT;

    float a16[16];
    short8_t bf[3];

    f32x4_t accCW[4];
#pragma unroll
    for (int S = 0; S < 4; ++S)
        accCW[S] = *(const f32x4_t*)&x[crow + 256 * S + DP];

#pragma unroll 1
    for (int k = 0; k < 4; ++k) {
        const int g = 4 * cw + 1 + k;
        const size_t grow = ((size_t)b * NN + g) * TT;
#pragma unroll
        for (int u = 0; u < 4; ++u) {
            float4 v = *(const float4*)&x[grow + 16 * tid + 4 * u];
#pragma unroll
            for (int e = 0; e < 4; ++e) {
                const float4 w = *(const float4*)&out[((size_t)b * NN + (4 * g + 1 + e)) * TT + 16 * tid + 4 * u];
                v.x += w.x; v.y += w.y; v.z += w.z; v.w += w.w;
            }
            a16[4*u+0] = v.x; a16[4*u+1] = v.y; a16[4*u+2] = v.z; a16[4*u+3] = v.w;
        }
        stage16(sab, a16, tid);
        load_bfrags(irfB, g, tid, bf);
        f32x4_t accT[4];
#pragma unroll
        for (int S = 0; S < 4; ++S) accT[S] = f32x4_t{0.f, 0.f, 0.f, 0.f};
        conv_mfma3(sab, bf, EB, accT);
#pragma unroll
        for (int S = 0; S < 4; ++S) {
            *(f32x4_t*)&out[grow + 256 * S + DP] = accT[S];
            accCW[S] += accT[S];
        }
    }

#pragma unroll
    for (int S = 0; S < 4; ++S) {
        short4_t s4;
#pragma unroll
        for (int q = 0; q < 4; ++q) s4[q] = f2bf(accCW[S][q]);
        *(short4_t*)&sab[swz(80 + 256 * S + DP)] = s4;
    }
    load_bfrags(irfB, cw, tid, bf);
    f32x4_t accB[4];
#pragma unroll
    for (int S = 0; S < 4; ++S) accB[S] = f32x4_t{0.f, 0.f, 0.f, 0.f};
    conv_mfma3(sab, bf, EB, accB);
#pragma unroll
    for (int S = 0; S < 4; ++S) {
        *(f32x4_t*)&out[crow + 256 * S + DP] = accB[S];
        *(f32x4_t*)&s_ch[wid][256 * S + DP]  = accB[S];
    }

    __syncthreads();

    if (wid == 0) {
        const size_t prow = ((size_t)b * NN + p) * TT;
#pragma unroll
        for (int u = 0; u < 4; ++u) {
            float4 v = *(const float4*)&x[prow + 16 * tid + 4 * u];
#pragma unroll
            for (int w2 = 0; w2 < 4; ++w2) {
                const float4 cc = *(const float4*)&s_ch[w2][16 * tid + 4 * u];
                v.x += cc.x; v.y += cc.y; v.z += cc.z; v.w += cc.w;
            }
            a16[4*u+0] = v.x; a16[4*u+1] = v.y; a16[4*u+2] = v.z; a16[4*u+3] = v.w;
        }
        stage16(sab, a16, tid);
        load_bfrags(irfB, p, tid, bf);
        f32x4_t accF[4];
#pragma unroll
        for (int S = 0; S < 4; ++S) accF[S] = f32x4_t{0.f, 0.f, 0.f, 0.f};
        conv_mfma3(sab, bf, EB, accF);
#pragma unroll
        for (int S = 0; S < 4; ++S)
            *(f32x4_t*)&out[prow + 256 * S + DP] = accF[S];
    }
}

// ================= scalar fp32 tail2 (L1 + root; large magnitudes) =================
__device__ __forceinline__ void load_rf(const float* __restrict__ irf, int n, float (&rf)[WW]) {
    const float* irp = irf + (size_t)n * WW;
#pragma unroll
    for (int i = 0; i < WW / 4; ++i) {
        const float4 f = *(const float4*)&irp[4 * i];
        rf[4*i+0] = f.x; rf[4*i+1] = f.y; rf[4*i+2] = f.z; rf[4*i+3] = f.w;
    }
}

__device__ __forceinline__ void wave_conv16(const float (&a)[16], const float (&rf)[WW],
                                            float (&y)[16], int tid)
{
#pragma unroll
    for (int j = 0; j < 16; ++j) y[j] = 0.0f;
#pragma unroll
    for (int m = 0; m < 16; ++m)
#pragma unroll
        for (int j = m; j < 16; ++j)
            y[j] += rf[j - m] * a[m];
#pragma unroll
    for (int d = 1; d <= 4; ++d) {
        float h[16];
#pragma unroll
        for (int m = 0; m < 16; ++m) {
            const float ha = __shfl(a[m], tid - d);
            h[m] = (tid >= d) ? ha : 0.0f;
        }
        if (d < 4) {
#pragma unroll
            for (int m = 0; m < 16; ++m)
#pragma unroll
                for (int j = 0; j < 16; ++j)
                    y[j] += rf[j + 16 * d - m] * h[m];
        } else {
#pragma unroll
            for (int m = 1; m < 16; ++m)
#pragma unroll
                for (int j = 0; j < m; ++j)
                    y[j] += rf[j + WW - m] * h[m];
        }
    }
}

__global__ __launch_bounds__(256) void route_tail2(
    const float* __restrict__ x, const float* __restrict__ irf,
    float* __restrict__ out)
{
    const int wid = threadIdx.x >> 6;
    const int tid = threadIdx.x & 63;
    const int b   = blockIdx.x;

    __shared__ __align__(16) float s_ch[4][TT];

    const int cw = 1 + wid;
    const size_t crow = ((size_t)b * NN + cw) * TT;
    const int loc = tid * 16;

    float rf[WW], a[16], y[16];

#pragma unroll
    for (int u = 0; u < 4; ++u) {
        float4 v = *(const float4*)&x[crow + loc + 4 * u];
#pragma unroll
        for (int e = 0; e < 4; ++e) {
            const float4 w = *(const float4*)&out[((size_t)b * NN + (4 * cw + 1 + e)) * TT + loc + 4 * u];
            v.x += w.x; v.y += w.y; v.z += w.z; v.w += w.w;
        }
        a[4*u+0] = v.x; a[4*u+1] = v.y; a[4*u+2] = v.z; a[4*u+3] = v.w;
    }
    load_rf(irf, cw, rf);
    wave_conv16(a, rf, y, tid);
#pragma unroll
    for (int u = 0; u < 4; ++u) {
        const float4 f = make_float4(y[4*u+0], y[4*u+1], y[4*u+2], y[4*u+3]);
        *(float4*)&out[crow + loc + 4 * u] = f;
        *(float4*)&s_ch[wid][loc + 4 * u]  = f;
    }

    __syncthreads();

    if (wid == 0) {
        const size_t prow = (size_t)b * NN * TT;
#pragma unroll
        for (int u = 0; u < 4; ++u) {
            float4 v = *(const float4*)&x[prow + loc + 4 * u];
#pragma unroll
            for (int w2 = 0; w2 < 4; ++w2) {
                const float4 cc = *(const float4*)&s_ch[w2][loc + 4 * u];
                v.x += cc.x; v.y += cc.y; v.z += cc.z; v.w += cc.w;
            }
            a[4*u+0] = v.x; a[4*u+1] = v.y; a[4*u+2] = v.z; a[4*u+3] = v.w;
        }
        load_rf(irf, 0, rf);
        wave_conv16(a, rf, y, tid);
#pragma unroll
        for (int u = 0; u < 4; ++u)
            *(float4*)&out[prow + loc + 4 * u] = make_float4(y[4*u+0], y[4*u+1], y[4*u+2], y[4*u+3]);
    }
}

extern "C" void kernel_launch(void* const* d_in, const int* in_sizes, int n_in,
                              void* d_out, int out_size, void* d_ws, size_t ws_size,
                              hipStream_t stream) {
    const float* x    = (const float*)d_in[0];
    const float* phys = (const float*)d_in[1];
    const float* w1   = (const float*)d_in[2];
    const float* b1   = (const float*)d_in[3];
    const float* w2   = (const float*)d_in[4];
    const float* b2   = (const float*)d_in[5];
    const float* w3   = (const float*)d_in[6];
    const float* b3   = (const float*)d_in[7];
    // d_in[8] = parent, d_in[9] = depth: fixed 4-ary heap tree (children 4n+1..4n+4)
    // levels: L0:0 L1:1-4 L2:5-20 L3:21-84 L4:85-340 L5:341-1364
    //         d6:1365-5460 (internal 1365-2047, leaves 2048-5460) d7:5461-8191 (leaves)

    float* out = (float*)d_out;
    // ws layout: irf fp32 [0,2MB) | irfB [4MB,+24MB)
    float* irf  = (float*)d_ws;
    short* irfB = (short*)((char*)d_ws + (4u << 20));

    mlp_mfma<<<512, 256, 0, stream>>>(phys, w1, b1, w2, b2, w3, b3, irf, irfB);

    // 1) fat pass: L6-int (1366) + L5-fused n=512..1364 (1706) + leaf 2048 (2) = 3074 tasks
    route_lf6p<<<(3074 + 3) / 4, 256, 0, stream>>>(x, irfB, out);
    // 2) mid-small: L5 nodes 341..511 (342 tasks), children from out
    route_mid_mfma<<<(342 + 3) / 4, 256, 0, stream>>>(x, irfB, out, 341, 342);
    // 3) L4+L3+L2 fused per L2 node (MFMA)
    route_tail3_mfma<<<32, 256, 0, stream>>>(x, irfB, out);
    // 4) L1+L0 (fp32 scalar, root precision)
    route_tail2<<<2, 256, 0, stream>>>(x, irf, out);
}